// Round 2
// baseline (885.502 us; speedup 1.0000x reference)
//
#include <hip/hip_runtime.h>
#include <hip/hip_bf16.h>
#include <math.h>

#define T_SEQ 2048
#define C3 3072
#define C_DIM 1024

typedef __bf16 bf16_t;
typedef __bf16 bf16x8 __attribute__((ext_vector_type(8)));
typedef __bf16 bf16x4_t __attribute__((ext_vector_type(4)));
typedef float f32x4 __attribute__((ext_vector_type(4)));

typedef __attribute__((address_space(1))) const void gconst_t;
typedef __attribute__((address_space(3))) void lds_t;

static __device__ __forceinline__ bf16x8 ldg8(const bf16_t* p) {
    return *reinterpret_cast<const bf16x8*>(p);
}

// f32->bf16 casts of x/qkv_w/proj_w + ews zeroing. Unit = one float4.
// 2,097,152 units. (dists moved to filler blocks inside the QKV GEMM.)
__global__ __launch_bounds__(256) void aux_kernel(const float* __restrict__ x,
                                                  const float* __restrict__ qw,
                                                  const float* __restrict__ pw,
                                                  bf16_t* __restrict__ xb,
                                                  bf16_t* __restrict__ wb,
                                                  bf16_t* __restrict__ pb,
                                                  float* __restrict__ ews) {
    long gid = (long)blockIdx.x * 256 + threadIdx.x;
    if (gid < 2) ews[gid] = 0.f;
    const float* src;
    bf16_t* dst;
    long u;
    if (gid < 1048576) { src = x; dst = xb; u = gid; }
    else if (gid < 1835008) { src = qw; dst = wb; u = gid - 1048576; }
    else { src = pw; dst = pb; u = gid - 1835008; }
    float4 v4 = ((const float4*)src)[u];
    bf16x4_t o;
    o[0] = (bf16_t)v4.x; o[1] = (bf16_t)v4.y; o[2] = (bf16_t)v4.z; o[3] = (bf16_t)v4.w;
    *(bf16x4_t*)(dst + u * 4) = o;
}

// C = A @ B^T, A[M,K], B[N,K] bf16 row-major. BMx128 tile, global_load_lds
// width-16 staging with chunk^=(row&7) XOR swizzle (unpadded LDS, conflict-free
// ds_read_b128). MFMA operands swapped so each lane holds 4 consecutive C cols.
//
// FUSE: blocks with blockIdx.y >= 32 are write-only fillers that run
// CONCURRENTLY with the GEMM blocks (GEMM is MFMA-bound, fillers are
// HBM-write-bound -> different pipes). fb < 1024: zero the attn rows this
// (bh,it) tile will never write (left distance-cutoff rect + causal rect,
// jskip formula identical to attn_kernel's). fb >= 1024: dists table rows.
// FIN: last y-row block 0 writes the two energy scalars (proj GEMM launch).
template <int BM, bool OUT_BF16, bool FUSE, bool FIN>
__global__ __launch_bounds__(256) void gemm_bt(const bf16_t* __restrict__ A,
                                               const bf16_t* __restrict__ Bw,
                                               void* __restrict__ Cout,
                                               int M, int N, int K,
                                               float* __restrict__ attn_zero,
                                               const float* __restrict__ dscales,
                                               float* __restrict__ dists,
                                               const float* __restrict__ ews,
                                               float* __restrict__ dout) {
    if (FIN) {
        if (blockIdx.y == gridDim.y - 1) {
            if (blockIdx.x == 0 && threadIdx.x == 0) {
                dout[4194304] = ews[0] / 65536.f;
                dout[4194305] = -ews[1] / 65536.f;
            }
            return;
        }
    }
    if (FUSE && blockIdx.y >= 32) {
        int fb = (blockIdx.y - 32) * gridDim.x + blockIdx.x;  // 64*24 = 1536
        int tid = threadIdx.x;
        f32x4 z4 = {0.f, 0.f, 0.f, 0.f};
        if (fb < 1024) {
            int bh = fb >> 5, it = fb & 31, h = bh & 15;
            float dsc = dscales[h];
            int jskip = 0;
            if (dsc > 1e-6f) {
                int keep = (int)(38.0f / dsc + 63.0f) >> 6;
                jskip = it - keep;
                if (jskip < 0) jskip = 0;
            }
            float* Ab = attn_zero + ((size_t)bh * T_SEQ + (it << 6)) * T_SEQ;
            int ln = jskip << 6;
            for (int r = 0; r < 64; ++r) {
                float* rowp = Ab + (size_t)r * T_SEQ;
                for (int c = tid << 2; c < ln; c += 1024)
                    __builtin_nontemporal_store(z4, (f32x4*)(rowp + c));
            }
            int zc0 = (it << 6) + 64, zn = T_SEQ - zc0;
            for (int r = 0; r < 64; ++r) {
                float* rowp = Ab + (size_t)r * T_SEQ + zc0;
                for (int c = tid << 2; c < zn; c += 1024)
                    __builtin_nontemporal_store(z4, (f32x4*)(rowp + c));
            }
        } else {
            int i0r = (fb - 1024) << 2;  // 512 blocks x 4 dists rows
            for (int rr = 0; rr < 4; ++rr) {
                int i = i0r + rr;
                float* rowp = dists + (size_t)i * T_SEQ;
                for (int c = tid << 2; c < T_SEQ; c += 1024) {
                    f32x4 o;
                    for (int k = 0; k < 4; ++k) {
                        int j = c + k;
                        o[k] = (float)(i > j ? i - j : j - i);
                    }
                    __builtin_nontemporal_store(o, (f32x4*)(rowp + c));
                }
            }
        }
        return;
    }

    constexpr int WM = BM / 2;
    constexpr int MI = WM / 16;
    __shared__ bf16_t sA[BM * 64];
    __shared__ bf16_t sB[128 * 64];
    int tid = threadIdx.x, lane = tid & 63, wid = tid >> 6;
    int m = lane & 15, quad = lane >> 4;
    int wm = (wid >> 1) * WM, wn = (wid & 1) * 64;
    int m0 = blockIdx.y * BM, n0 = blockIdx.x * 128;
    int lrow = lane >> 3, cxor = (lane & 7) ^ (lrow & 7);

    const bf16_t* Ag = A + (size_t)(m0 + wid * 8 + lrow) * K + cxor * 8;
    const bf16_t* Bg = Bw + (size_t)(n0 + wid * 8 + lrow) * K + cxor * 8;

    f32x4 acc[MI][4] = {};
    for (int k0 = 0; k0 < K; k0 += 64) {
        for (int p = 0; p < BM / 32; ++p)
            __builtin_amdgcn_global_load_lds((gconst_t*)(Ag + (size_t)(p * 32) * K + k0),
                                             (lds_t*)(sA + (p * 32 + wid * 8) * 64), 16, 0, 0);
        for (int p = 0; p < 4; ++p)
            __builtin_amdgcn_global_load_lds((gconst_t*)(Bg + (size_t)(p * 32) * K + k0),
                                             (lds_t*)(sB + (p * 32 + wid * 8) * 64), 16, 0, 0);
        __syncthreads();
        for (int ks = 0; ks < 2; ++ks) {
            bf16x8 a[MI], b[4];
            for (int i = 0; i < MI; ++i) {
                int r = wm + i * 16 + m;
                a[i] = *(const bf16x8*)(sA + r * 64 + ((((ks << 2) + quad) ^ (r & 7)) << 3));
            }
            for (int j = 0; j < 4; ++j) {
                int r = wn + j * 16 + m;
                b[j] = *(const bf16x8*)(sB + r * 64 + ((((ks << 2) + quad) ^ (r & 7)) << 3));
            }
            for (int i = 0; i < MI; ++i)
                for (int j = 0; j < 4; ++j)
                    acc[i][j] = __builtin_amdgcn_mfma_f32_16x16x32_bf16(b[j], a[i], acc[i][j], 0, 0, 0);
        }
        __syncthreads();
    }
    for (int i = 0; i < MI; ++i)
        for (int j = 0; j < 4; ++j) {
            size_t row = m0 + wm + i * 16 + m;
            int col = n0 + wn + j * 16 + quad * 4;
            if (OUT_BF16) {
                bf16x4_t o;
                for (int r = 0; r < 4; ++r) o[r] = (bf16_t)acc[i][j][r];
                *(bf16x4_t*)((bf16_t*)Cout + row * N + col) = o;
            } else {
                *(f32x4*)((float*)Cout + row * N + col) = acc[i][j];
            }
        }
}

// V (qkv cols [2048 + h*64 .. +64)) -> Vt[bh][d][t], LDS 64x64 transpose
__global__ __launch_bounds__(256) void repack_vt(const bf16_t* __restrict__ qkv,
                                                 bf16_t* __restrict__ vt) {
    __shared__ bf16_t s[64][72];
    int t0 = (blockIdx.x & 31) << 6;
    int bh = blockIdx.x >> 5;
    int b = bh >> 4, h = bh & 15;
    int tid = threadIdx.x;
    int r = tid >> 3, c8 = (tid & 7) << 3;
    const bf16_t* src = qkv + (size_t)(b * T_SEQ) * C3 + 2048 + h * 64;
    for (int p = 0; p < 2; ++p) {
        int t = r + p * 32;
        *(uint4*)&s[t][c8] = *(const uint4*)&src[(size_t)(t0 + t) * C3 + c8];
    }
    __syncthreads();
    bf16_t* dst = vt + (size_t)bh * 64 * T_SEQ;
    for (int p = 0; p < 2; ++p) {
        int d = r + p * 32;
        bf16x8 vv;
        for (int i = 0; i < 8; ++i) vv[i] = s[c8 + i][d];
        *(bf16x8*)&dst[(size_t)d * T_SEQ + t0 + c8] = vv;
    }
}

// one block = one (b,h, 64-row tile). Each lane owns one fixed attn row
// i = w16 + (lane&15) (swapped-operand MFMA). Pass 1 (barrier-free, no LDS):
// row denominators — no max needed, |s_qk| <= 8 bound. Pass 2: nt float4 attn
// stores, energies via  sum p*ln p = sum p*v - ln(lsum)  (no per-entry log),
// P@V via sP round-trip. Tiles with distance penalty > 38 (p <= ~1e-12)
// are skipped; their zero region (and the causal rect) is written by the
// filler blocks fused into the QKV GEMM launch — this kernel writes ONLY the
// computed region [jskip*64, i0+64).
__global__ __launch_bounds__(256) void attn_kernel(const bf16_t* __restrict__ qkv,
                                                   const bf16_t* __restrict__ vt,
                                                   const float* __restrict__ dscales,
                                                   float* __restrict__ attn,
                                                   bf16_t* __restrict__ y,
                                                   float* __restrict__ ews) {
    __shared__ bf16_t sP[64][72];
    __shared__ float sred[8];
    // remap: blocks i and i+256 (same CU under round-robin) get it summing 31
    int base = blockIdx.x & 31;
    int bh = blockIdx.x >> 5;
    int it = (bh & 8) ? (31 - base) : base;
    int b = bh >> 4, h = bh & 15;
    int i0 = it << 6;
    int tid = threadIdx.x, lane = tid & 63, wid = tid >> 6;
    int m = lane & 15, quad = lane >> 4;
    int w16 = wid << 4;
    float dsc = dscales[h];
    const float scale = 0.125f;

    // negligible-tile cutoff: skip jt with (it-jt)*64-63 > 38/dsc
    int jskip = 0;
    if (dsc > 1e-6f) {
        int keep = (int)(38.0f / dsc + 63.0f) >> 6;
        jskip = it - keep;
        if (jskip < 0) jskip = 0;
    }

    const bf16_t* Qb = qkv + (size_t)(b * T_SEQ) * C3 + h * 64;
    const bf16_t* Kb = Qb + 1024;
    const bf16_t* Vb = vt + (size_t)bh * 64 * T_SEQ;
    float* Ab = attn + ((size_t)bh * T_SEQ + i0) * T_SEQ;

    int i = i0 + w16 + m;  // this lane's fixed attn row
    bf16x8 qf[2];
    qf[0] = ldg8(Qb + (size_t)i * C3 + quad * 8);
    qf[1] = ldg8(Qb + (size_t)i * C3 + 32 + quad * 8);

    // ---- pass 1: row denominators (no barriers, no LDS) ----
    float lsum = 0.f;
    for (int jt = jskip; jt <= it; ++jt) {
        int j0 = jt << 6;
        f32x4 acc[4] = {};
        for (int ks = 0; ks < 2; ++ks)
            for (int n = 0; n < 4; ++n) {
                bf16x8 kf = ldg8(Kb + (size_t)(j0 + n * 16 + m) * C3 + ks * 32 + quad * 8);
                acc[n] = __builtin_amdgcn_mfma_f32_16x16x32_bf16(kf, qf[ks], acc[n], 0, 0, 0);
            }
        if (jt < it) {
            for (int n = 0; n < 4; ++n)
                for (int r = 0; r < 4; ++r) {
                    float d = (float)(i - (j0 + n * 16 + quad * 4 + r));
                    lsum += __expf(acc[n][r] * scale - dsc * d);
                }
        } else {
            for (int n = 0; n < 4; ++n)
                for (int r = 0; r < 4; ++r) {
                    int j = j0 + n * 16 + quad * 4 + r;
                    if (j <= i) lsum += __expf(acc[n][r] * scale - dsc * (float)(i - j));
                }
        }
    }
    lsum += __shfl_xor(lsum, 16);
    lsum += __shfl_xor(lsum, 32);
    float rl = 1.f / lsum;

    // ---- pass 2: write attn (nt float4), energies, P@V ----
    f32x4 oacc[4] = {};
    float e_d = 0.f;
    float e_e = (quad == 0) ? -__logf(lsum) : 0.f;  // per-row ln(rl), once

    for (int jt = jskip; jt <= it; ++jt) {
        int j0 = jt << 6;
        f32x4 acc[4] = {};
        for (int ks = 0; ks < 2; ++ks)
            for (int n = 0; n < 4; ++n) {
                bf16x8 kf = ldg8(Kb + (size_t)(j0 + n * 16 + m) * C3 + ks * 32 + quad * 8);
                acc[n] = __builtin_amdgcn_mfma_f32_16x16x32_bf16(kf, qf[ks], acc[n], 0, 0, 0);
            }
        bool diag = (jt == it);
        for (int n = 0; n < 4; ++n) {
            f32x4 pv;
            for (int r = 0; r < 4; ++r) {
                int j = j0 + n * 16 + quad * 4 + r;
                float p = 0.f;
                if (!diag || j <= i) {
                    float d = (float)(i - j);
                    float v = acc[n][r] * scale - dsc * d;
                    p = __expf(v) * rl;
                    e_d += p * d;
                    e_e += p * v;   // sum p*v; + ln(rl) added once per row
                }
                pv[r] = p;
            }
            __builtin_nontemporal_store(
                pv, (f32x4*)(Ab + (size_t)(w16 + m) * T_SEQ + j0 + n * 16 + quad * 4));
            bf16x4_t pb;
            for (int r = 0; r < 4; ++r) pb[r] = (bf16_t)pv[r];
            *(bf16x4_t*)&sP[w16 + m][n * 16 + quad * 4] = pb;
        }
        // no barrier: sP stripe [w16, w16+16) is written and read by this wave
        // only; compiler-inserted lgkmcnt orders the ds_write -> ds_read.
        for (int ks = 0; ks < 2; ++ks) {
            bf16x8 pf = *(const bf16x8*)&sP[w16 + m][ks * 32 + quad * 8];
            for (int n = 0; n < 4; ++n) {
                bf16x8 vf = ldg8(Vb + (size_t)(n * 16 + m) * T_SEQ + j0 + ks * 32 + quad * 8);
                oacc[n] = __builtin_amdgcn_mfma_f32_16x16x32_bf16(vf, pf, oacc[n], 0, 0, 0);
            }
        }
    }

    // oacc[n]: rows d = n*16+quad*4+r, col i  -> y[i][h*64+d], bf16x4 stores
    for (int n = 0; n < 4; ++n) {
        bf16x4_t o;
        for (int r = 0; r < 4; ++r) o[r] = (bf16_t)oacc[n][r];
        *(bf16x4_t*)(y + (size_t)(b * T_SEQ + i) * C_DIM + h * 64 + n * 16 + quad * 4) = o;
    }

    for (int off = 1; off < 64; off <<= 1) {
        e_d += __shfl_xor(e_d, off);
        e_e += __shfl_xor(e_e, off);
    }
    if (lane == 0) { sred[wid] = e_d; sred[wid + 4] = e_e; }
    __syncthreads();
    if (tid == 0) {
        atomicAdd(ews, sred[0] + sred[1] + sred[2] + sred[3]);
        atomicAdd(ews + 1, sred[4] + sred[5] + sred[6] + sred[7]);
    }
}

extern "C" void kernel_launch(void* const* d_in, const int* in_sizes, int n_in,
                              void* d_out, int out_size, void* d_ws, size_t ws_size,
                              hipStream_t stream) {
    const float* x = (const float*)d_in[0];
    const float* qkv_w = (const float*)d_in[1];
    const float* proj_w = (const float*)d_in[2];
    const float* dscales = (const float*)d_in[3];
    float* out = (float*)d_out;

    char* ws = (char*)d_ws;
    float* ews   = (float*)ws;                      // 2 floats (pad to 256B)
    bf16_t* xb   = (bf16_t*)(ws + 256);             // 4,194,304
    bf16_t* wb   = xb + 4194304;                    // 3,145,728
    bf16_t* pb   = wb + 3145728;                    // 1,048,576
    bf16_t* qkvb = pb + 1048576;                    // 12,582,912
    bf16_t* vtb  = qkvb + 12582912;                 // 4,194,304
    bf16_t* yb   = vtb + 4194304;                   // 4,194,304  (~58.8 MB total)

    float* attn_out = out + 4194306;
    float* dists_out = out + 138412034;

    aux_kernel<<<8192, 256, 0, stream>>>(x, qkv_w, proj_w, xb, wb, pb, ews);
    // y < 32: QKV GEMM (24x32 = 768 blocks). y in [32,96): 1536 filler blocks
    // (1024 attn-zero tiles + 512 dists blocks) overlapping the GEMM.
    gemm_bt<128, true, true, false><<<dim3(24, 96), 256, 0, stream>>>(
        xb, wb, qkvb, 4096, 3072, 1024, attn_out, dscales, dists_out, nullptr, nullptr);
    repack_vt<<<1024, 256, 0, stream>>>(qkvb, vtb);
    attn_kernel<<<1024, 256, 0, stream>>>(qkvb, vtb, dscales, attn_out, yb, ews);
    // y < 64: proj GEMM (8x64 = 512 blocks). y == 64: finalize block.
    gemm_bt<64, false, false, true><<<dim3(8, 65), 256, 0, stream>>>(
        yb, pb, out, 4096, 1024, 1024, nullptr, nullptr, nullptr, ews, out);
}

// Round 3
// 778.047 us; speedup vs baseline: 1.1381x; 1.1381x over previous
//
#include <hip/hip_runtime.h>
#include <hip/hip_bf16.h>
#include <math.h>

#define T_SEQ 2048
#define C3 3072
#define C_DIM 1024

typedef __bf16 bf16_t;
typedef __bf16 bf16x8 __attribute__((ext_vector_type(8)));
typedef __bf16 bf16x4_t __attribute__((ext_vector_type(4)));
typedef float f32x4 __attribute__((ext_vector_type(4)));
typedef _Float16 h16x4 __attribute__((ext_vector_type(4)));

typedef __attribute__((address_space(1))) const void gconst_t;
typedef __attribute__((address_space(3))) void lds_t;

static __device__ __forceinline__ bf16x8 ldg8(const bf16_t* p) {
    return *reinterpret_cast<const bf16x8*>(p);
}

// One launch: f32->bf16 casts of x/qkv_w/proj_w, dists output, ews zeroing.
// Unit = one float4 (cvt) or one f32x4 of dists. 3,145,728 units total.
__global__ __launch_bounds__(256) void aux_kernel(const float* __restrict__ x,
                                                  const float* __restrict__ qw,
                                                  const float* __restrict__ pw,
                                                  bf16_t* __restrict__ xb,
                                                  bf16_t* __restrict__ wb,
                                                  bf16_t* __restrict__ pb,
                                                  float* __restrict__ dout,
                                                  float* __restrict__ ews) {
    long gid = (long)blockIdx.x * 256 + threadIdx.x;
    if (gid < 2) ews[gid] = 0.f;
    const float* src;
    bf16_t* dst;
    long u;
    if (gid < 1048576) { src = x; dst = xb; u = gid; }
    else if (gid < 1835008) { src = qw; dst = wb; u = gid - 1048576; }
    else if (gid < 2097152) { src = pw; dst = pb; u = gid - 1835008; }
    else {
        long v = gid - 2097152;           // dists: 4 consecutive cols of one row
        long e0 = v << 2;
        int i = (int)(e0 >> 11), j0 = (int)(e0 & 2047);
        f32x4 o;
        for (int r = 0; r < 4; ++r) {
            int j = j0 + r;
            o[r] = (float)(i > j ? i - j : j - i);
        }
        __builtin_nontemporal_store(o, (f32x4*)(dout + e0));
        return;
    }
    float4 v4 = ((const float4*)src)[u];
    bf16x4_t o;
    o[0] = (bf16_t)v4.x; o[1] = (bf16_t)v4.y; o[2] = (bf16_t)v4.z; o[3] = (bf16_t)v4.w;
    *(bf16x4_t*)(dst + u * 4) = o;
}

// C = A @ B^T, A[M,K], B[N,K] bf16 row-major. BMx128 tile, global_load_lds
// width-16 staging with chunk^=(row&7) XOR swizzle (unpadded LDS, conflict-free
// ds_read_b128). MFMA operands swapped so each lane holds 4 consecutive C cols.
// FIN: last y-row block 0 writes the two energy scalars (proj GEMM launch).
template <int BM, bool OUT_BF16, bool FIN>
__global__ __launch_bounds__(256) void gemm_bt(const bf16_t* __restrict__ A,
                                               const bf16_t* __restrict__ Bw,
                                               void* __restrict__ Cout,
                                               int M, int N, int K,
                                               const float* __restrict__ ews,
                                               float* __restrict__ dout) {
    if (FIN) {
        if (blockIdx.y == gridDim.y - 1) {
            if (blockIdx.x == 0 && threadIdx.x == 0) {
                dout[4194304] = ews[0] / 65536.f;
                dout[4194305] = -ews[1] / 65536.f;
            }
            return;
        }
    }
    constexpr int WM = BM / 2;
    constexpr int MI = WM / 16;
    __shared__ bf16_t sA[BM * 64];
    __shared__ bf16_t sB[128 * 64];
    int tid = threadIdx.x, lane = tid & 63, wid = tid >> 6;
    int m = lane & 15, quad = lane >> 4;
    int wm = (wid >> 1) * WM, wn = (wid & 1) * 64;
    int m0 = blockIdx.y * BM, n0 = blockIdx.x * 128;
    int lrow = lane >> 3, cxor = (lane & 7) ^ (lrow & 7);

    const bf16_t* Ag = A + (size_t)(m0 + wid * 8 + lrow) * K + cxor * 8;
    const bf16_t* Bg = Bw + (size_t)(n0 + wid * 8 + lrow) * K + cxor * 8;

    f32x4 acc[MI][4] = {};
    for (int k0 = 0; k0 < K; k0 += 64) {
        for (int p = 0; p < BM / 32; ++p)
            __builtin_amdgcn_global_load_lds((gconst_t*)(Ag + (size_t)(p * 32) * K + k0),
                                             (lds_t*)(sA + (p * 32 + wid * 8) * 64), 16, 0, 0);
        for (int p = 0; p < 4; ++p)
            __builtin_amdgcn_global_load_lds((gconst_t*)(Bg + (size_t)(p * 32) * K + k0),
                                             (lds_t*)(sB + (p * 32 + wid * 8) * 64), 16, 0, 0);
        __syncthreads();
        for (int ks = 0; ks < 2; ++ks) {
            bf16x8 a[MI], b[4];
            for (int i = 0; i < MI; ++i) {
                int r = wm + i * 16 + m;
                a[i] = *(const bf16x8*)(sA + r * 64 + ((((ks << 2) + quad) ^ (r & 7)) << 3));
            }
            for (int j = 0; j < 4; ++j) {
                int r = wn + j * 16 + m;
                b[j] = *(const bf16x8*)(sB + r * 64 + ((((ks << 2) + quad) ^ (r & 7)) << 3));
            }
            for (int i = 0; i < MI; ++i)
                for (int j = 0; j < 4; ++j)
                    acc[i][j] = __builtin_amdgcn_mfma_f32_16x16x32_bf16(b[j], a[i], acc[i][j], 0, 0, 0);
        }
        __syncthreads();
    }
    for (int i = 0; i < MI; ++i)
        for (int j = 0; j < 4; ++j) {
            size_t row = m0 + wm + i * 16 + m;
            int col = n0 + wn + j * 16 + quad * 4;
            if (OUT_BF16) {
                bf16x4_t o;
                for (int r = 0; r < 4; ++r) o[r] = (bf16_t)acc[i][j][r];
                *(bf16x4_t*)((bf16_t*)Cout + row * N + col) = o;
            } else {
                *(f32x4*)((float*)Cout + row * N + col) = acc[i][j];
            }
        }
}

// V (qkv cols [2048 + h*64 .. +64)) -> Vt[bh][d][t], LDS 64x64 transpose
__global__ __launch_bounds__(256) void repack_vt(const bf16_t* __restrict__ qkv,
                                                 bf16_t* __restrict__ vt) {
    __shared__ bf16_t s[64][72];
    int t0 = (blockIdx.x & 31) << 6;
    int bh = blockIdx.x >> 5;
    int b = bh >> 4, h = bh & 15;
    int tid = threadIdx.x;
    int r = tid >> 3, c8 = (tid & 7) << 3;
    const bf16_t* src = qkv + (size_t)(b * T_SEQ) * C3 + 2048 + h * 64;
    for (int p = 0; p < 2; ++p) {
        int t = r + p * 32;
        *(uint4*)&s[t][c8] = *(const uint4*)&src[(size_t)(t0 + t) * C3 + c8];
    }
    __syncthreads();
    bf16_t* dst = vt + (size_t)bh * 64 * T_SEQ;
    for (int p = 0; p < 2; ++p) {
        int d = r + p * 32;
        bf16x8 vv;
        for (int i = 0; i < 8; ++i) vv[i] = s[c8 + i][d];
        *(bf16x8*)&dst[(size_t)d * T_SEQ + t0 + c8] = vv;
    }
}

// SINGLE-PASS attention. One block = one (b,h, 64-row tile); lane owns row
// i = w16 + (lane&15) (swapped-operand MFMA). Per tile: QK^T MFMA once,
// p~ = exp(v) once; accumulate lsum / sum(p~ d) / sum(p~ v) in f32; PV runs
// immediately with UNNORMALIZED p~ (oacc *= rl at the end — MFMA is linear);
// p~ cached as fp16 (rel err 2^-11, p~ <= e^8 << fp16 max) in 56 VGPRs for
// up to 7 tiles (all that survive the distance cutoff when dsc >= ~0.086).
// Emission = pure NT f32x4 stores of (float)p~_h * rl. Tiles beyond the
// 7-tile cache window (only when dsc is tiny) take a recompute fallback.
// Energies: e_d = rl*sum(p~ d); e_e = rl*sum(p~ v) - ln(lsum) per row.
__global__ __launch_bounds__(256) void attn_kernel(const bf16_t* __restrict__ qkv,
                                                   const bf16_t* __restrict__ vt,
                                                   const float* __restrict__ dscales,
                                                   float* __restrict__ attn,
                                                   bf16_t* __restrict__ y,
                                                   float* __restrict__ ews) {
    __shared__ bf16_t sP[64][72];
    __shared__ float sred[8];
    // remap: blocks i and i+256 (same CU under round-robin) get it summing 31
    int base = blockIdx.x & 31;
    int bh = blockIdx.x >> 5;
    int it = (bh & 8) ? (31 - base) : base;
    int b = bh >> 4, h = bh & 15;
    int i0 = it << 6;
    int tid = threadIdx.x, lane = tid & 63, wid = tid >> 6;
    int m = lane & 15, quad = lane >> 4;
    int w16 = wid << 4;
    float dsc = dscales[h];
    const float scale = 0.125f;

    // negligible-tile cutoff: skip jt with (it-jt)*64-63 > 38/dsc
    int jskip = 0;
    if (dsc > 1e-6f) {
        int keep = (int)(38.0f / dsc + 63.0f) >> 6;
        jskip = it - keep;
        if (jskip < 0) jskip = 0;
    }

    const bf16_t* Qb = qkv + (size_t)(b * T_SEQ) * C3 + h * 64;
    const bf16_t* Kb = Qb + 1024;
    const bf16_t* Vb = vt + (size_t)bh * 64 * T_SEQ;
    float* Ab = attn + ((size_t)bh * T_SEQ + i0) * T_SEQ;

    // zero fills FIRST (R0 ordering measured best): left skipped rect
    // [0, jskip*64), causal rect [i0+64, 2048).
    {
        f32x4 z4 = {0.f, 0.f, 0.f, 0.f};
        int ln = jskip << 6;
        for (int r = 0; r < 64; ++r) {
            float* rowp = Ab + (size_t)r * T_SEQ;
            for (int c = tid << 2; c < ln; c += 1024)
                __builtin_nontemporal_store(z4, (f32x4*)(rowp + c));
        }
        int zc0 = i0 + 64, zn = T_SEQ - zc0;
        for (int r = 0; r < 64; ++r) {
            float* rowp = Ab + (size_t)r * T_SEQ + zc0;
            for (int c = tid << 2; c < zn; c += 1024)
                __builtin_nontemporal_store(z4, (f32x4*)(rowp + c));
        }
    }

    int i = i0 + w16 + m;  // this lane's fixed attn row
    bf16x8 qf[2];
    qf[0] = ldg8(Qb + (size_t)i * C3 + quad * 8);
    qf[1] = ldg8(Qb + (size_t)i * C3 + 32 + quad * 8);

    int nt = it - jskip + 1;
    int ovf = nt > 7 ? nt - 7 : 0;
    int jc0 = jskip + ovf;  // first register-cached tile

    float lsum = 0.f, edt = 0.f, eet = 0.f;
    f32x4 oacc[4] = {};
    h16x4 cache[7][4];

#define TILE_BODY(JT, CSTMT)                                                              \
    {                                                                                     \
        int j0 = (JT) << 6;                                                               \
        f32x4 acc[4] = {};                                                                \
        for (int ks = 0; ks < 2; ++ks)                                                    \
            for (int n = 0; n < 4; ++n) {                                                 \
                bf16x8 kf = ldg8(Kb + (size_t)(j0 + n * 16 + m) * C3 + ks * 32 + quad * 8); \
                acc[n] = __builtin_amdgcn_mfma_f32_16x16x32_bf16(kf, qf[ks], acc[n], 0, 0, 0); \
            }                                                                             \
        bool diag = ((JT) == it);                                                         \
        for (int n = 0; n < 4; ++n) {                                                     \
            bf16x4_t pbv;                                                                 \
            h16x4 ph;                                                                     \
            for (int r = 0; r < 4; ++r) {                                                 \
                int j = j0 + n * 16 + quad * 4 + r;                                       \
                float p = 0.f;                                                            \
                if (!diag || j <= i) {                                                    \
                    float d = (float)(i - j);                                             \
                    float v = acc[n][r] * scale - dsc * d;                                \
                    p = __expf(v);                                                        \
                    lsum += p; edt += p * d; eet += p * v;                                \
                }                                                                         \
                pbv[r] = (bf16_t)p; ph[r] = (_Float16)p;                                  \
            }                                                                             \
            *(bf16x4_t*)&sP[w16 + m][n * 16 + quad * 4] = pbv;                            \
            CSTMT;                                                                        \
        }                                                                                 \
        for (int ks = 0; ks < 2; ++ks) {                                                  \
            bf16x8 pf = *(const bf16x8*)&sP[w16 + m][ks * 32 + quad * 8];                 \
            for (int n = 0; n < 4; ++n) {                                                 \
                bf16x8 vf = ldg8(Vb + (size_t)(n * 16 + m) * T_SEQ + j0 + ks * 32 + quad * 8); \
                oacc[n] = __builtin_amdgcn_mfma_f32_16x16x32_bf16(vf, pf, oacc[n], 0, 0, 0); \
            }                                                                             \
        }                                                                                 \
    }

    // overflow tiles (general small-dsc case; 0 iterations on the bench)
    for (int jt = jskip; jt < jc0; ++jt) {
        TILE_BODY(jt, (void)0)
    }
    // cached tiles: unrolled so cache[tix][n] is statically indexed (no scratch)
#pragma unroll
    for (int tix = 0; tix < 7; ++tix) {
        int jt = jc0 + tix;
        if (jt <= it) {
            TILE_BODY(jt, cache[tix][n] = ph)
        }
    }
#undef TILE_BODY

    lsum += __shfl_xor(lsum, 16);
    lsum += __shfl_xor(lsum, 32);
    float rl = 1.f / lsum;

    // ---- emission: overflow recompute (never diag; jt < jc0 <= it) ----
    for (int jt = jskip; jt < jc0; ++jt) {
        int j0 = jt << 6;
        f32x4 acc[4] = {};
        for (int ks = 0; ks < 2; ++ks)
            for (int n = 0; n < 4; ++n) {
                bf16x8 kf = ldg8(Kb + (size_t)(j0 + n * 16 + m) * C3 + ks * 32 + quad * 8);
                acc[n] = __builtin_amdgcn_mfma_f32_16x16x32_bf16(kf, qf[ks], acc[n], 0, 0, 0);
            }
        for (int n = 0; n < 4; ++n) {
            f32x4 pv;
            for (int r = 0; r < 4; ++r) {
                int j = j0 + n * 16 + quad * 4 + r;
                float d = (float)(i - j);
                pv[r] = __expf(acc[n][r] * scale - dsc * d) * rl;
            }
            __builtin_nontemporal_store(
                pv, (f32x4*)(Ab + (size_t)(w16 + m) * T_SEQ + j0 + n * 16 + quad * 4));
        }
    }
    // ---- emission: cached tiles — pure NT stores ----
#pragma unroll
    for (int tix = 0; tix < 7; ++tix) {
        int jt = jc0 + tix;
        if (jt <= it) {
            int j0 = jt << 6;
            for (int n = 0; n < 4; ++n) {
                h16x4 ph = cache[tix][n];
                f32x4 pv;
                for (int r = 0; r < 4; ++r) pv[r] = (float)ph[r] * rl;
                __builtin_nontemporal_store(
                    pv, (f32x4*)(Ab + (size_t)(w16 + m) * T_SEQ + j0 + n * 16 + quad * 4));
            }
        }
    }

    // oacc[n]: rows d = n*16+quad*4+r, col i -> y[i][h*64+d]; scale by rl here
    for (int n = 0; n < 4; ++n) {
        bf16x4_t o;
        for (int r = 0; r < 4; ++r) o[r] = (bf16_t)(oacc[n][r] * rl);
        *(bf16x4_t*)(y + (size_t)(b * T_SEQ + i) * C_DIM + h * 64 + n * 16 + quad * 4) = o;
    }

    float e_d = rl * edt;
    float e_e = rl * eet + ((quad == 0) ? -__logf(lsum) : 0.f);

    for (int off = 1; off < 64; off <<= 1) {
        e_d += __shfl_xor(e_d, off);
        e_e += __shfl_xor(e_e, off);
    }
    if (lane == 0) { sred[wid] = e_d; sred[wid + 4] = e_e; }
    __syncthreads();
    if (tid == 0) {
        atomicAdd(ews, sred[0] + sred[1] + sred[2] + sred[3]);
        atomicAdd(ews + 1, sred[4] + sred[5] + sred[6] + sred[7]);
    }
}

extern "C" void kernel_launch(void* const* d_in, const int* in_sizes, int n_in,
                              void* d_out, int out_size, void* d_ws, size_t ws_size,
                              hipStream_t stream) {
    const float* x = (const float*)d_in[0];
    const float* qkv_w = (const float*)d_in[1];
    const float* proj_w = (const float*)d_in[2];
    const float* dscales = (const float*)d_in[3];
    float* out = (float*)d_out;

    char* ws = (char*)d_ws;
    float* ews   = (float*)ws;                      // 2 floats (pad to 256B)
    bf16_t* xb   = (bf16_t*)(ws + 256);             // 4,194,304
    bf16_t* wb   = xb + 4194304;                    // 3,145,728
    bf16_t* pb   = wb + 3145728;                    // 1,048,576
    bf16_t* qkvb = pb + 1048576;                    // 12,582,912
    bf16_t* vtb  = qkvb + 12582912;                 // 4,194,304
    bf16_t* yb   = vtb + 4194304;                   // 4,194,304  (~58.8 MB total)

    float* attn_out = out + 4194306;
    float* dists_out = out + 138412034;

    aux_kernel<<<12288, 256, 0, stream>>>(x, qkv_w, proj_w, xb, wb, pb, dists_out, ews);
    gemm_bt<128, true, false><<<dim3(24, 32), 256, 0, stream>>>(
        xb, wb, qkvb, 4096, 3072, 1024, nullptr, nullptr);
    repack_vt<<<1024, 256, 0, stream>>>(qkvb, vtb);
    attn_kernel<<<1024, 256, 0, stream>>>(qkvb, vtb, dscales, attn_out, yb, ews);
    // y < 64: proj GEMM (8x64 = 512 blocks). y == 64: finalize block.
    gemm_bt<64, false, true><<<dim3(8, 65), 256, 0, stream>>>(
        yb, pb, out, 4096, 1024, 1024, ews, out);
}